// Round 1
// baseline (1085.461 us; speedup 1.0000x reference)
//
#include <hip/hip_runtime.h>
#include <hip/hip_bf16.h>

// GQA prefill: B=1, T=2048, DIM=4096, H=32, KV=8, D=128, causal.
// Pipeline: cvt fp32->bf16 -> Q/K/V proj (bf16 MFMA GEMM) -> V transpose ->
//           flash attention (bf16 MFMA) -> O proj (fp32 out).

#define T_SEQ 2048
#define DIM 4096
#define NH 32
#define NKV 8
#define HD 128

typedef unsigned short ushort_t;
using f32x4 = __attribute__((ext_vector_type(4))) float;
using bf16x8 = __attribute__((ext_vector_type(8))) __bf16;

#define DEVINLINE __device__ __forceinline__

DEVINLINE ushort f2bf(float f) {
  union { float f; unsigned u; } a; a.f = f;
  unsigned u = a.u;
  u += 0x7fffu + ((u >> 16) & 1u);   // RNE
  return (ushort)(u >> 16);
}

DEVINLINE bf16x8 ld_frag(const ushort* p) { return *(const bf16x8*)p; }

DEVINLINE f32x4 mfma16(bf16x8 a, bf16x8 b, f32x4 c) {
  return __builtin_amdgcn_mfma_f32_16x16x32_bf16(a, b, c, 0, 0, 0);
}

DEVINLINE void async_ld16(const void* g, void* l) {
  __builtin_amdgcn_global_load_lds(
      (__attribute__((address_space(1))) void*)(g),
      (__attribute__((address_space(3))) void*)(l), 16, 0, 0);
}

DEVINLINE void store_c(float* p, float v) { *p = v; }
DEVINLINE void store_c(ushort* p, float v) { *p = f2bf(v); }

// ---------------- fp32 -> bf16 conversion ----------------
__global__ void cvt_f32_bf16(const float* __restrict__ in, ushort* __restrict__ out, int n) {
  int idx = blockIdx.x * blockDim.x + threadIdx.x;
  int stride = gridDim.x * blockDim.x;
  for (int i = idx * 4; i < n; i += stride * 4) {
    float4 f = *(const float4*)(in + i);
    ushort4 u;
    u.x = f2bf(f.x); u.y = f2bf(f.y); u.z = f2bf(f.z); u.w = f2bf(f.w);
    *(ushort4*)(out + i) = u;
  }
}

// ---------------- GEMM: C[M][N] = A[M][K] * B[N][K]^T  (m97 structure) ----------------
// 128x128 tile, BK=32, 256 threads = 4 waves (2x2), each wave 64x64 (4x4 MFMA 16x16x32).
template <typename OutT>
__global__ __launch_bounds__(256) void gemm_bt(const ushort* __restrict__ A,
                                               const ushort* __restrict__ B,
                                               OutT* __restrict__ C,
                                               int M, int N, int K) {
  __shared__ __align__(16) ushort lds_a[128 * 32];
  __shared__ __align__(16) ushort lds_b[128 * 32];
  const int tid = threadIdx.x;
  const int w = tid >> 6, lane = tid & 63;
  const int wm = w >> 1, wn = w & 1;
  const int lo = lane & 15, hi = lane >> 4;
  const int m0 = blockIdx.y * 128, n0 = blockIdx.x * 128;
  const int srow = lane >> 2;        // 0..15 (row within 16-row stripe)
  const int scol = (lane & 3) * 8;   // k-chunk (8 bf16 = 16B)
  f32x4 acc[4][4] = {};

  const ushort* Ab = A + (size_t)m0 * K;
  const ushort* Bb = B + (size_t)n0 * K;

  for (int k0 = 0; k0 < K; k0 += 32) {
    // stage 128x32 A and B tiles; LDS dest is wave-uniform base + lane*16
#pragma unroll
    for (int it = 0; it < 2; ++it) {
      const int rb = it * 64 + w * 16;
      async_ld16(Ab + (size_t)(rb + srow) * K + k0 + scol, &lds_a[rb * 32]);
      async_ld16(Bb + (size_t)(rb + srow) * K + k0 + scol, &lds_b[rb * 32]);
    }
    __syncthreads();
    bf16x8 af[4], bfr[4];
#pragma unroll
    for (int i = 0; i < 4; i++) af[i]  = ld_frag(&lds_a[(wm * 64 + i * 16 + lo) * 32 + hi * 8]);
#pragma unroll
    for (int i = 0; i < 4; i++) bfr[i] = ld_frag(&lds_b[(wn * 64 + i * 16 + lo) * 32 + hi * 8]);
#pragma unroll
    for (int mi = 0; mi < 4; mi++)
#pragma unroll
      for (int ni = 0; ni < 4; ni++)
        acc[mi][ni] = mfma16(af[mi], bfr[ni], acc[mi][ni]);
    __syncthreads();
  }
  // epilogue: C layout col=lane&15, row=(lane>>4)*4+reg  [m89-verified]
#pragma unroll
  for (int mi = 0; mi < 4; mi++)
#pragma unroll
    for (int ni = 0; ni < 4; ni++) {
      const int col = n0 + wn * 64 + ni * 16 + lo;
#pragma unroll
      for (int r = 0; r < 4; r++) {
        const int row = m0 + wm * 64 + mi * 16 + hi * 4 + r;
        store_c(&C[(size_t)row * N + col], acc[mi][ni][r]);
      }
    }
}

// ---------------- V transpose: v[T][1024] -> vt[8][128][T] ----------------
__global__ __launch_bounds__(256) void transpose_v(const ushort* __restrict__ v,
                                                   ushort* __restrict__ vt) {
  __shared__ ushort tile[64][65];
  const int c0 = blockIdx.x * 64;   // col (kv*128+d) tile
  const int t0 = blockIdx.y * 64;   // time tile
  const int tid = threadIdx.x;
#pragma unroll
  for (int i = 0; i < 16; i++) {
    int idx = tid + i * 256;
    int r = idx >> 6, c = idx & 63;
    tile[r][c] = v[(size_t)(t0 + r) * (NKV * HD) + c0 + c];
  }
  __syncthreads();
#pragma unroll
  for (int i = 0; i < 16; i++) {
    int idx = tid + i * 256;
    int dr = idx >> 6, dc = idx & 63;  // dr: local col(d), dc: local t
    int gc = c0 + dr;
    int kv = gc >> 7, d = gc & 127;
    vt[(size_t)kv * HD * T_SEQ + (size_t)d * T_SEQ + t0 + dc] = tile[dc][dr];
  }
}

// ---------------- flash attention (causal, GQA) ----------------
// grid (32 q-tiles, 32 heads); 4 waves/block, wave w owns q rows [qt*64+w*16, +16).
__global__ __launch_bounds__(256) void attn_fused(const ushort* __restrict__ q,   // [T][4096]
                                                  const ushort* __restrict__ k,   // [T][1024]
                                                  const ushort* __restrict__ vt,  // [8][128][T]
                                                  ushort* __restrict__ o) {       // [T][4096]
  __shared__ __align__(16) ushort p_lds[4][16][88];  // 88: 16B-aligned rows, ~2-way banks
  const int qt = blockIdx.x;
  const int h = blockIdx.y;
  const int kvh = h >> 2;  // GROUP=4, h = kv*4 + g
  const int w = threadIdx.x >> 6, lane = threadIdx.x & 63;
  const int lo = lane & 15, hi = lane >> 4;
  const int q0 = qt * 64 + w * 16;

  // Q fragments (A operand): lane holds Q[q0+lo][kk*32 + hi*8 .. +8]
  bf16x8 aq[4];
  const ushort* qrow = q + (size_t)(q0 + lo) * DIM + h * HD;
#pragma unroll
  for (int kk = 0; kk < 4; kk++) aq[kk] = ld_frag(qrow + kk * 32 + hi * 8);

  f32x4 oacc[8] = {};
  float m_r[4], l_r[4];
#pragma unroll
  for (int r = 0; r < 4; r++) { m_r[r] = -__builtin_inff(); l_r[r] = 0.f; }

  const float sc = 0.08838834764831845f;  // 1/sqrt(128)
  const ushort* kbase = k + kvh * HD;
  const ushort* vbase = vt + (size_t)kvh * HD * T_SEQ;

  for (int t = 0; t <= qt; ++t) {
    const int k0 = t * 64;
    // S[16 q][64 kv] = Q * K^T
    f32x4 s[4] = {};
#pragma unroll
    for (int cb = 0; cb < 4; cb++) {
      const ushort* krow = kbase + (size_t)(k0 + cb * 16 + lo) * (NKV * HD);
#pragma unroll
      for (int kk = 0; kk < 4; kk++)
        s[cb] = mfma16(aq[kk], ld_frag(krow + kk * 32 + hi * 8), s[cb]);
    }
    // scale + causal mask (diagonal tile only)
#pragma unroll
    for (int cb = 0; cb < 4; cb++)
#pragma unroll
      for (int r = 0; r < 4; r++) {
        float v = s[cb][r] * sc;
        if (t == qt && (k0 + cb * 16 + lo) > (q0 + hi * 4 + r)) v = -__builtin_inff();
        s[cb][r] = v;
      }
    // online softmax; row R=hi*4+r lives in 16-lane group (shfl_xor 1,2,4,8 stays in-group)
#pragma unroll
    for (int r = 0; r < 4; r++) {
      float mx = fmaxf(fmaxf(s[0][r], s[1][r]), fmaxf(s[2][r], s[3][r]));
      mx = fmaxf(mx, __shfl_xor(mx, 1));
      mx = fmaxf(mx, __shfl_xor(mx, 2));
      mx = fmaxf(mx, __shfl_xor(mx, 4));
      mx = fmaxf(mx, __shfl_xor(mx, 8));
      float mnew = fmaxf(m_r[r], mx);
      float corr = __expf(m_r[r] - mnew);
      float rs = 0.f;
#pragma unroll
      for (int cb = 0; cb < 4; cb++) {
        float p = __expf(s[cb][r] - mnew);
        s[cb][r] = p; rs += p;
      }
      rs += __shfl_xor(rs, 1); rs += __shfl_xor(rs, 2);
      rs += __shfl_xor(rs, 4); rs += __shfl_xor(rs, 8);
      l_r[r] = l_r[r] * corr + rs;
      m_r[r] = mnew;
#pragma unroll
      for (int db = 0; db < 8; db++) oacc[db][r] *= corr;
    }
    // P (C-layout) -> LDS -> A-layout fragments
#pragma unroll
    for (int cb = 0; cb < 4; cb++)
#pragma unroll
      for (int r = 0; r < 4; r++)
        p_lds[w][hi * 4 + r][cb * 16 + lo] = f2bf(s[cb][r]);
    bf16x8 ap[2];
#pragma unroll
    for (int ks = 0; ks < 2; ks++) ap[ks] = ld_frag(&p_lds[w][lo][ks * 32 + hi * 8]);
    // O += P * V   (Vt rows are d, contiguous in t -> same A*B^T form)
#pragma unroll
    for (int db = 0; db < 8; db++) {
      const ushort* vrow = vbase + (size_t)(db * 16 + lo) * T_SEQ + k0;
#pragma unroll
      for (int ks = 0; ks < 2; ks++)
        oacc[db] = mfma16(ap[ks], ld_frag(vrow + ks * 32 + hi * 8), oacc[db]);
    }
  }
  // write O (bf16) for the O-projection GEMM
#pragma unroll
  for (int db = 0; db < 8; db++)
#pragma unroll
    for (int r = 0; r < 4; r++) {
      float v = oacc[db][r] / l_r[r];
      o[(size_t)(q0 + hi * 4 + r) * DIM + h * HD + db * 16 + lo] = f2bf(v);
    }
}

// ---------------- launch ----------------
extern "C" void kernel_launch(void* const* d_in, const int* in_sizes, int n_in,
                              void* d_out, int out_size, void* d_ws, size_t ws_size,
                              hipStream_t stream) {
  const float* x  = (const float*)d_in[0];
  const float* wq = (const float*)d_in[1];
  const float* wk = (const float*)d_in[2];
  const float* wv = (const float*)d_in[3];
  const float* wo = (const float*)d_in[4];
  float* out = (float*)d_out;

  char* ws = (char*)d_ws;
  size_t off = 0;
  auto alloc = [&](size_t elems) {
    ushort* p = (ushort*)(ws + off);
    off += ((elems * 2 + 255) & ~(size_t)255);
    return p;
  };
  ushort* xb  = alloc((size_t)T_SEQ * DIM);
  ushort* wqb = alloc((size_t)DIM * DIM);
  ushort* wkb = alloc((size_t)NKV * HD * DIM);
  ushort* wvb = alloc((size_t)NKV * HD * DIM);
  ushort* wob = alloc((size_t)DIM * DIM);
  ushort* qb  = alloc((size_t)T_SEQ * DIM);
  ushort* kb  = alloc((size_t)T_SEQ * NKV * HD);
  ushort* vb  = alloc((size_t)T_SEQ * NKV * HD);
  ushort* vtb = alloc((size_t)NKV * HD * T_SEQ);
  ushort* ab  = alloc((size_t)T_SEQ * DIM);

  auto cvt = [&](const float* src, ushort* dst, size_t n) {
    size_t want = (n / 4 + 255) / 256;
    int blocks = (int)(want < 2048 ? want : 2048);
    cvt_f32_bf16<<<blocks, 256, 0, stream>>>(src, dst, (int)n);
  };
  cvt(x,  xb,  (size_t)T_SEQ * DIM);
  cvt(wq, wqb, (size_t)DIM * DIM);
  cvt(wk, wkb, (size_t)NKV * HD * DIM);
  cvt(wv, wvb, (size_t)NKV * HD * DIM);
  cvt(wo, wob, (size_t)DIM * DIM);

  gemm_bt<ushort><<<dim3(DIM / 128, T_SEQ / 128), 256, 0, stream>>>(xb, wqb, qb, T_SEQ, DIM, DIM);
  gemm_bt<ushort><<<dim3(NKV * HD / 128, T_SEQ / 128), 256, 0, stream>>>(xb, wkb, kb, T_SEQ, NKV * HD, DIM);
  gemm_bt<ushort><<<dim3(NKV * HD / 128, T_SEQ / 128), 256, 0, stream>>>(xb, wvb, vb, T_SEQ, NKV * HD, DIM);
  transpose_v<<<dim3(NKV * HD / 64, T_SEQ / 64), 256, 0, stream>>>(vb, vtb);
  attn_fused<<<dim3(T_SEQ / 64, NH), 256, 0, stream>>>(qb, kb, vtb, ab);
  gemm_bt<float><<<dim3(DIM / 128, T_SEQ / 128), 256, 0, stream>>>(ab, wob, out, T_SEQ, DIM, DIM);
}

// Round 5
// 627.622 us; speedup vs baseline: 1.7295x; 1.7295x over previous
//
#include <hip/hip_runtime.h>
#include <hip/hip_bf16.h>

// GQA prefill: B=1, T=2048, DIM=4096, H=32, KV=8, D=128, causal.
// cvt fp32->bf16 -> fused QKV proj (bf16 MFMA) -> V transpose ->
// flash attention v2 (LDS-staged K/V, balanced causal pairs) -> O proj.

#define T_SEQ 2048
#define DIM 4096
#define NH 32
#define NKV 8
#define HD 128

using f32x4 = __attribute__((ext_vector_type(4))) float;
using bf16x8 = __attribute__((ext_vector_type(8))) __bf16;

#define DEVINLINE __device__ __forceinline__

DEVINLINE ushort f2bf(float f) {
  union { float f; unsigned u; } a; a.f = f;
  unsigned u = a.u;
  u += 0x7fffu + ((u >> 16) & 1u);   // RNE
  return (ushort)(u >> 16);
}

DEVINLINE bf16x8 ld_frag(const ushort* p) { return *(const bf16x8*)p; }

DEVINLINE f32x4 mfma16(bf16x8 a, bf16x8 b, f32x4 c) {
  return __builtin_amdgcn_mfma_f32_16x16x32_bf16(a, b, c, 0, 0, 0);
}

DEVINLINE void async_ld16(const void* g, void* l) {
  __builtin_amdgcn_global_load_lds(
      (__attribute__((address_space(1))) void*)(g),
      (__attribute__((address_space(3))) void*)(l), 16, 0, 0);
}

DEVINLINE void store_c(float* p, float v) { *p = v; }
DEVINLINE void store_c(ushort* p, float v) { *p = f2bf(v); }

// ---------------- fp32 -> bf16 conversion ----------------
__global__ void cvt_f32_bf16(const float* __restrict__ in, ushort* __restrict__ out, int n) {
  int idx = blockIdx.x * blockDim.x + threadIdx.x;
  int stride = gridDim.x * blockDim.x;
  for (int i = idx * 4; i < n; i += stride * 4) {
    float4 f = *(const float4*)(in + i);
    ushort4 u;
    u.x = f2bf(f.x); u.y = f2bf(f.y); u.z = f2bf(f.z); u.w = f2bf(f.w);
    *(ushort4*)(out + i) = u;
  }
}

// ---------------- fused QKV GEMM: [2048x4096] x {wq,wk,wv}^T ----------------
// 128x128 tile, BK=32, 4 waves. bx 0..31 -> Q, 32..39 -> K, 40..47 -> V.
__global__ __launch_bounds__(256) void gemm_qkv(const ushort* __restrict__ A,
                                                const ushort* __restrict__ wq,
                                                const ushort* __restrict__ wk,
                                                const ushort* __restrict__ wv,
                                                ushort* __restrict__ qo,
                                                ushort* __restrict__ ko,
                                                ushort* __restrict__ vo) {
  __shared__ __align__(16) ushort lds_a[128 * 32];
  __shared__ __align__(16) ushort lds_b[128 * 32];
  const int K = DIM;
  const int bx = blockIdx.x;
  const ushort* B; ushort* C; int n0, Nc;
  if (bx < 32)      { B = wq + (size_t)bx * 128 * K;        C = qo; n0 = bx * 128;        Nc = DIM; }
  else if (bx < 40) { B = wk + (size_t)(bx - 32) * 128 * K; C = ko; n0 = (bx - 32) * 128; Nc = NKV * HD; }
  else              { B = wv + (size_t)(bx - 40) * 128 * K; C = vo; n0 = (bx - 40) * 128; Nc = NKV * HD; }

  const int tid = threadIdx.x;
  const int w = tid >> 6, lane = tid & 63;
  const int wm = w >> 1, wn = w & 1;
  const int lo = lane & 15, hi = lane >> 4;
  const int m0 = blockIdx.y * 128;
  const int srow = lane >> 2;
  const int scol = (lane & 3) * 8;
  f32x4 acc[4][4] = {};
  const ushort* Ab = A + (size_t)m0 * K;

  for (int k0 = 0; k0 < K; k0 += 32) {
#pragma unroll
    for (int it = 0; it < 2; ++it) {
      const int rb = it * 64 + w * 16;
      async_ld16(Ab + (size_t)(rb + srow) * K + k0 + scol, &lds_a[rb * 32]);
      async_ld16(B  + (size_t)(rb + srow) * K + k0 + scol, &lds_b[rb * 32]);
    }
    __syncthreads();
    bf16x8 af[4], bfr[4];
#pragma unroll
    for (int i = 0; i < 4; i++) af[i]  = ld_frag(&lds_a[(wm * 64 + i * 16 + lo) * 32 + hi * 8]);
#pragma unroll
    for (int i = 0; i < 4; i++) bfr[i] = ld_frag(&lds_b[(wn * 64 + i * 16 + lo) * 32 + hi * 8]);
#pragma unroll
    for (int mi = 0; mi < 4; mi++)
#pragma unroll
      for (int ni = 0; ni < 4; ni++)
        acc[mi][ni] = mfma16(af[mi], bfr[ni], acc[mi][ni]);
    __syncthreads();
  }
#pragma unroll
  for (int mi = 0; mi < 4; mi++)
#pragma unroll
    for (int ni = 0; ni < 4; ni++) {
      const int col = n0 + wn * 64 + ni * 16 + lo;
#pragma unroll
      for (int r = 0; r < 4; r++) {
        const int row = m0 + wm * 64 + mi * 16 + hi * 4 + r;
        C[(size_t)row * Nc + col] = f2bf(acc[mi][ni][r]);
      }
    }
}

// ---------------- generic GEMM (O projection) ----------------
template <typename OutT>
__global__ __launch_bounds__(256) void gemm_bt(const ushort* __restrict__ A,
                                               const ushort* __restrict__ B,
                                               OutT* __restrict__ C,
                                               int M, int N, int K) {
  __shared__ __align__(16) ushort lds_a[128 * 32];
  __shared__ __align__(16) ushort lds_b[128 * 32];
  const int tid = threadIdx.x;
  const int w = tid >> 6, lane = tid & 63;
  const int wm = w >> 1, wn = w & 1;
  const int lo = lane & 15, hi = lane >> 4;
  const int m0 = blockIdx.y * 128, n0 = blockIdx.x * 128;
  const int srow = lane >> 2;
  const int scol = (lane & 3) * 8;
  f32x4 acc[4][4] = {};
  const ushort* Ab = A + (size_t)m0 * K;
  const ushort* Bb = B + (size_t)n0 * K;

  for (int k0 = 0; k0 < K; k0 += 32) {
#pragma unroll
    for (int it = 0; it < 2; ++it) {
      const int rb = it * 64 + w * 16;
      async_ld16(Ab + (size_t)(rb + srow) * K + k0 + scol, &lds_a[rb * 32]);
      async_ld16(Bb + (size_t)(rb + srow) * K + k0 + scol, &lds_b[rb * 32]);
    }
    __syncthreads();
    bf16x8 af[4], bfr[4];
#pragma unroll
    for (int i = 0; i < 4; i++) af[i]  = ld_frag(&lds_a[(wm * 64 + i * 16 + lo) * 32 + hi * 8]);
#pragma unroll
    for (int i = 0; i < 4; i++) bfr[i] = ld_frag(&lds_b[(wn * 64 + i * 16 + lo) * 32 + hi * 8]);
#pragma unroll
    for (int mi = 0; mi < 4; mi++)
#pragma unroll
      for (int ni = 0; ni < 4; ni++)
        acc[mi][ni] = mfma16(af[mi], bfr[ni], acc[mi][ni]);
    __syncthreads();
  }
#pragma unroll
  for (int mi = 0; mi < 4; mi++)
#pragma unroll
    for (int ni = 0; ni < 4; ni++) {
      const int col = n0 + wn * 64 + ni * 16 + lo;
#pragma unroll
      for (int r = 0; r < 4; r++) {
        const int row = m0 + wm * 64 + mi * 16 + hi * 4 + r;
        store_c(&C[(size_t)row * N + col], acc[mi][ni][r]);
      }
    }
}

// ---------------- V transpose: v[T][1024] -> vt[8][128][T] ----------------
__global__ __launch_bounds__(256) void transpose_v(const ushort* __restrict__ v,
                                                   ushort* __restrict__ vt) {
  __shared__ ushort tile[64][65];
  const int c0 = blockIdx.x * 64;
  const int t0 = blockIdx.y * 64;
  const int tid = threadIdx.x;
#pragma unroll
  for (int i = 0; i < 16; i++) {
    int idx = tid + i * 256;
    int r = idx >> 6, c = idx & 63;
    tile[r][c] = v[(size_t)(t0 + r) * (NKV * HD) + c0 + c];
  }
  __syncthreads();
#pragma unroll
  for (int i = 0; i < 16; i++) {
    int idx = tid + i * 256;
    int dr = idx >> 6, dc = idx & 63;
    int gc = c0 + dr;
    int kv = gc >> 7, d = gc & 127;
    vt[(size_t)kv * HD * T_SEQ + (size_t)d * T_SEQ + t0 + dc] = tile[dc][dr];
  }
}

// ---------------- flash attention v2 ----------------
// grid (32 qpairs, 8 kvh, 2 headpairs); 256 thr = 4 waves.
// Block handles q-tiles {p, 63-p} (32 rows each) for 2 heads of the GQA group.
// Wave w: head = kvh*4 + hp*2 + (w>>1), q-rows sub-tile (w&1)*16.
// K (64x128) and V^T (128x64) staged in LDS, XOR-swizzled, reg-prefetched (T14).
__global__ __launch_bounds__(256) void attn_fused2(const ushort* __restrict__ q,   // [T][4096]
                                                   const ushort* __restrict__ k,   // [T][1024]
                                                   const ushort* __restrict__ vt,  // [8][128][T]
                                                   ushort* __restrict__ o) {       // [T][4096]
  __shared__ __align__(16) char sK[64 * 256];    // K[r][c]: byte r*256 + ((c*2)^((r&7)<<4))
  __shared__ __align__(16) char sV[128 * 128];   // Vt[d][t]: byte d*128 + ((t*2)^((d&7)<<4))
  __shared__ __align__(16) ushort sP[4][16][72];

  const int pr  = blockIdx.x;
  const int kvh = blockIdx.y;
  const int hp  = blockIdx.z;
  const int tid = threadIdx.x;
  const int w = tid >> 6, lane = tid & 63;
  const int lo = lane & 15, hi = lane >> 4;
  const int head = (kvh << 2) + (hp << 1) + (w >> 1);
  const int qsub = w & 1;

  const ushort* kbase = k + kvh * HD;
  const ushort* vbase = vt + (size_t)kvh * HD * T_SEQ;

  uint4 pk[4], pv[4];
  // issue global loads for tile at k0 (keeps them in regs; vmcnt waited at commit)
  auto issue = [&](int k0) {
#pragma unroll
    for (int j = 0; j < 4; ++j) {
      const int i = tid + j * 256;
      const int r = i >> 4, cbyte = (i & 15) << 4;
      pk[j] = *(const uint4*)(kbase + (size_t)(k0 + r) * (NKV * HD) + (cbyte >> 1));
      const int d = i >> 3, tbyte = (i & 7) << 4;
      pv[j] = *(const uint4*)(vbase + (size_t)d * T_SEQ + k0 + (tbyte >> 1));
    }
  };
  auto commit = [&]() {
#pragma unroll
    for (int j = 0; j < 4; ++j) {
      const int i = tid + j * 256;
      const int r = i >> 4, cbyte = (i & 15) << 4;
      *(uint4*)(sK + r * 256 + (cbyte ^ ((r & 7) << 4))) = pk[j];
      const int d = i >> 3, tbyte = (i & 7) << 4;
      *(uint4*)(sV + d * 128 + (tbyte ^ ((d & 7) << 4))) = pv[j];
    }
  };

  bf16x8 aq[4];
  f32x4 oacc[8];
  float m_r[4], l_r[4];
  const float sc = 0.08838834764831845f;  // 1/sqrt(128)

  auto load_q = [&](int qt) {
    const ushort* qp = q + (size_t)(qt * 32 + qsub * 16 + lo) * DIM + head * HD;
#pragma unroll
    for (int kk = 0; kk < 4; ++kk) aq[kk] = ld_frag(qp + kk * 32 + hi * 8);
  };
  auto reset_state = [&]() {
#pragma unroll
    for (int r = 0; r < 4; ++r) { m_r[r] = -__builtin_inff(); l_r[r] = 0.f; }
#pragma unroll
    for (int db = 0; db < 8; ++db) oacc[db] = (f32x4){0.f, 0.f, 0.f, 0.f};
  };
  auto write_out = [&](int qt) {
    const int row0 = qt * 32 + qsub * 16;
#pragma unroll
    for (int db = 0; db < 8; ++db)
#pragma unroll
      for (int r = 0; r < 4; ++r) {
        float v = oacc[db][r] / l_r[r];
        o[(size_t)(row0 + hi * 4 + r) * DIM + head * HD + db * 16 + lo] = f2bf(v);
      }
  };

  const int qtA = pr, qtB = 63 - pr;
  const int ntA = qtA / 2 + 1, ntB = qtB / 2 + 1;
  const int total = ntA + ntB;

  // prologue: stage tile (A, t=0)
  issue(0);
  commit();
  __syncthreads();
  load_q(qtA);
  reset_state();

  int phase = 0, nt = ntA, qt = qtA, t = 0;
  for (int i = 0; i < total; ++i) {
    const bool last = (t == nt - 1);
    const bool have_next = (i + 1 < total);
    if (have_next) issue(last ? 0 : (t + 1) * 64);

    const int k0 = t * 64;
    // ---- S = Q K^T ----
    f32x4 s[4] = {};
    __builtin_amdgcn_s_setprio(1);
#pragma unroll
    for (int cb = 0; cb < 4; ++cb) {
      const char* kr = sK + (cb * 16 + lo) * 256;
      const int swz = (lo & 7) << 4;
#pragma unroll
      for (int kk = 0; kk < 4; ++kk) {
        bf16x8 bk = *(const bf16x8*)(kr + ((kk * 64 + hi * 16) ^ swz));
        s[cb] = mfma16(aq[kk], bk, s[cb]);
      }
    }
    __builtin_amdgcn_s_setprio(0);
    // ---- scale + causal mask (last tile of phase only) ----
    const int row0 = qt * 32 + qsub * 16 + hi * 4;
#pragma unroll
    for (int cb = 0; cb < 4; ++cb)
#pragma unroll
      for (int r = 0; r < 4; ++r) {
        float v = s[cb][r] * sc;
        if (last && (k0 + cb * 16 + lo) > (row0 + r)) v = -__builtin_inff();
        s[cb][r] = v;
      }
    // ---- online softmax (rows live in 16-lane groups) ----
#pragma unroll
    for (int r = 0; r < 4; ++r) {
      float mx = fmaxf(fmaxf(s[0][r], s[1][r]), fmaxf(s[2][r], s[3][r]));
      mx = fmaxf(mx, __shfl_xor(mx, 1));
      mx = fmaxf(mx, __shfl_xor(mx, 2));
      mx = fmaxf(mx, __shfl_xor(mx, 4));
      mx = fmaxf(mx, __shfl_xor(mx, 8));
      float mnew = fmaxf(m_r[r], mx);
      float corr = __expf(m_r[r] - mnew);
      float rs = 0.f;
#pragma unroll
      for (int cb = 0; cb < 4; ++cb) {
        float p = __expf(s[cb][r] - mnew);
        s[cb][r] = p; rs += p;
      }
      rs += __shfl_xor(rs, 1); rs += __shfl_xor(rs, 2);
      rs += __shfl_xor(rs, 4); rs += __shfl_xor(rs, 8);
      l_r[r] = l_r[r] * corr + rs;
      m_r[r] = mnew;
#pragma unroll
      for (int db = 0; db < 8; ++db) oacc[db][r] *= corr;
    }
    // ---- P -> LDS -> A-frag ----
#pragma unroll
    for (int cb = 0; cb < 4; ++cb)
#pragma unroll
      for (int r = 0; r < 4; ++r)
        sP[w][hi * 4 + r][cb * 16 + lo] = f2bf(s[cb][r]);
    bf16x8 ap[2];
#pragma unroll
    for (int ks = 0; ks < 2; ++ks) ap[ks] = ld_frag(&sP[w][lo][ks * 32 + hi * 8]);
    // ---- O += P V ----
    __builtin_amdgcn_s_setprio(1);
#pragma unroll
    for (int db = 0; db < 8; ++db) {
      const char* vr = sV + (db * 16 + lo) * 128;
      const int swz = (lo & 7) << 4;
#pragma unroll
      for (int ks = 0; ks < 2; ++ks) {
        bf16x8 bv = *(const bf16x8*)(vr + ((ks * 64 + hi * 16) ^ swz));
        oacc[db] = mfma16(ap[ks], bv, oacc[db]);
      }
    }
    __builtin_amdgcn_s_setprio(0);

    __syncthreads();
    if (have_next) commit();
    __syncthreads();

    if (last) {
      write_out(qt);
      if (phase == 0) {
        phase = 1; nt = ntB; qt = qtB; t = 0;
        load_q(qtB);
        reset_state();
      }
    } else {
      ++t;
    }
  }
}

// ---------------- launch ----------------
extern "C" void kernel_launch(void* const* d_in, const int* in_sizes, int n_in,
                              void* d_out, int out_size, void* d_ws, size_t ws_size,
                              hipStream_t stream) {
  const float* x  = (const float*)d_in[0];
  const float* wq = (const float*)d_in[1];
  const float* wk = (const float*)d_in[2];
  const float* wv = (const float*)d_in[3];
  const float* wo = (const float*)d_in[4];
  float* out = (float*)d_out;

  char* ws = (char*)d_ws;
  size_t off = 0;
  auto alloc = [&](size_t elems) {
    ushort* p = (ushort*)(ws + off);
    off += ((elems * 2 + 255) & ~(size_t)255);
    return p;
  };
  ushort* xb  = alloc((size_t)T_SEQ * DIM);
  ushort* wqb = alloc((size_t)DIM * DIM);
  ushort* wkb = alloc((size_t)NKV * HD * DIM);
  ushort* wvb = alloc((size_t)NKV * HD * DIM);
  ushort* wob = alloc((size_t)DIM * DIM);
  ushort* qb  = alloc((size_t)T_SEQ * DIM);
  ushort* kb  = alloc((size_t)T_SEQ * NKV * HD);
  ushort* vb  = alloc((size_t)T_SEQ * NKV * HD);
  ushort* vtb = alloc((size_t)NKV * HD * T_SEQ);
  ushort* ab  = alloc((size_t)T_SEQ * DIM);

  auto cvt = [&](const float* src, ushort* dst, size_t n) {
    size_t want = (n / 4 + 255) / 256;
    int blocks = (int)(want < 2048 ? want : 2048);
    cvt_f32_bf16<<<blocks, 256, 0, stream>>>(src, dst, (int)n);
  };
  cvt(x,  xb,  (size_t)T_SEQ * DIM);
  cvt(wq, wqb, (size_t)DIM * DIM);
  cvt(wk, wkb, (size_t)NKV * HD * DIM);
  cvt(wv, wvb, (size_t)NKV * HD * DIM);
  cvt(wo, wob, (size_t)DIM * DIM);

  gemm_qkv<<<dim3(48, 16), 256, 0, stream>>>(xb, wqb, wkb, wvb, qb, kb, vb);
  transpose_v<<<dim3(NKV * HD / 64, T_SEQ / 64), 256, 0, stream>>>(vb, vtb);
  attn_fused2<<<dim3(32, NKV, 2), 256, 0, stream>>>(qb, kb, vtb, ab);
  gemm_bt<float><<<dim3(DIM / 128, T_SEQ / 128), 256, 0, stream>>>(ab, wob, out, T_SEQ, DIM, DIM);
}

// Round 7
// 535.180 us; speedup vs baseline: 2.0282x; 1.1727x over previous
//
#include <hip/hip_runtime.h>
#include <hip/hip_bf16.h>

// GQA prefill: B=1, T=2048, DIM=4096, H=32, KV=8, D=128, causal.
// cvt fp32->bf16 -> fused QKV proj (bf16 MFMA) -> V transpose ->
// flash attention v3 (scratch-free reg staging) -> O proj.

#define T_SEQ 2048
#define DIM 4096
#define NH 32
#define NKV 8
#define HD 128

using f32x4 = __attribute__((ext_vector_type(4))) float;
using bf16x8 = __attribute__((ext_vector_type(8))) __bf16;

#define DEVINLINE __device__ __forceinline__

DEVINLINE ushort f2bf(float f) {
  union { float f; unsigned u; } a; a.f = f;
  unsigned u = a.u;
  u += 0x7fffu + ((u >> 16) & 1u);   // RNE
  return (ushort)(u >> 16);
}

DEVINLINE bf16x8 ld_frag(const ushort* p) { return *(const bf16x8*)p; }

DEVINLINE f32x4 mfma16(bf16x8 a, bf16x8 b, f32x4 c) {
  return __builtin_amdgcn_mfma_f32_16x16x32_bf16(a, b, c, 0, 0, 0);
}

DEVINLINE void async_ld16(const void* g, void* l) {
  __builtin_amdgcn_global_load_lds(
      (__attribute__((address_space(1))) void*)(g),
      (__attribute__((address_space(3))) void*)(l), 16, 0, 0);
}

DEVINLINE void store_c(float* p, float v) { *p = v; }
DEVINLINE void store_c(ushort* p, float v) { *p = f2bf(v); }

// ---------------- fp32 -> bf16 conversion ----------------
__global__ void cvt_f32_bf16(const float* __restrict__ in, ushort* __restrict__ out, int n) {
  int idx = blockIdx.x * blockDim.x + threadIdx.x;
  int stride = gridDim.x * blockDim.x;
  for (int i = idx * 4; i < n; i += stride * 4) {
    float4 f = *(const float4*)(in + i);
    ushort4 u;
    u.x = f2bf(f.x); u.y = f2bf(f.y); u.z = f2bf(f.z); u.w = f2bf(f.w);
    *(ushort4*)(out + i) = u;
  }
}

// ---------------- fused QKV GEMM: [2048x4096] x {wq,wk,wv}^T ----------------
// 128x128 tile, BK=32, 4 waves. bx 0..31 -> Q, 32..39 -> K, 40..47 -> V.
__global__ __launch_bounds__(256) void gemm_qkv(const ushort* __restrict__ A,
                                                const ushort* __restrict__ wq,
                                                const ushort* __restrict__ wk,
                                                const ushort* __restrict__ wv,
                                                ushort* __restrict__ qo,
                                                ushort* __restrict__ ko,
                                                ushort* __restrict__ vo) {
  __shared__ __align__(16) ushort lds_a[128 * 32];
  __shared__ __align__(16) ushort lds_b[128 * 32];
  const int K = DIM;
  const int bx = blockIdx.x;
  const ushort* B; ushort* C; int n0, Nc;
  if (bx < 32)      { B = wq + (size_t)bx * 128 * K;        C = qo; n0 = bx * 128;        Nc = DIM; }
  else if (bx < 40) { B = wk + (size_t)(bx - 32) * 128 * K; C = ko; n0 = (bx - 32) * 128; Nc = NKV * HD; }
  else              { B = wv + (size_t)(bx - 40) * 128 * K; C = vo; n0 = (bx - 40) * 128; Nc = NKV * HD; }

  const int tid = threadIdx.x;
  const int w = tid >> 6, lane = tid & 63;
  const int wm = w >> 1, wn = w & 1;
  const int lo = lane & 15, hi = lane >> 4;
  const int m0 = blockIdx.y * 128;
  const int srow = lane >> 2;
  const int scol = (lane & 3) * 8;
  f32x4 acc[4][4] = {};
  const ushort* Ab = A + (size_t)m0 * K;

  for (int k0 = 0; k0 < K; k0 += 32) {
#pragma unroll
    for (int it = 0; it < 2; ++it) {
      const int rb = it * 64 + w * 16;
      async_ld16(Ab + (size_t)(rb + srow) * K + k0 + scol, &lds_a[rb * 32]);
      async_ld16(B  + (size_t)(rb + srow) * K + k0 + scol, &lds_b[rb * 32]);
    }
    __syncthreads();
    bf16x8 af[4], bfr[4];
#pragma unroll
    for (int i = 0; i < 4; i++) af[i]  = ld_frag(&lds_a[(wm * 64 + i * 16 + lo) * 32 + hi * 8]);
#pragma unroll
    for (int i = 0; i < 4; i++) bfr[i] = ld_frag(&lds_b[(wn * 64 + i * 16 + lo) * 32 + hi * 8]);
#pragma unroll
    for (int mi = 0; mi < 4; mi++)
#pragma unroll
      for (int ni = 0; ni < 4; ni++)
        acc[mi][ni] = mfma16(af[mi], bfr[ni], acc[mi][ni]);
    __syncthreads();
  }
#pragma unroll
  for (int mi = 0; mi < 4; mi++)
#pragma unroll
    for (int ni = 0; ni < 4; ni++) {
      const int col = n0 + wn * 64 + ni * 16 + lo;
#pragma unroll
      for (int r = 0; r < 4; r++) {
        const int row = m0 + wm * 64 + mi * 16 + hi * 4 + r;
        C[(size_t)row * Nc + col] = f2bf(acc[mi][ni][r]);
      }
    }
}

// ---------------- generic GEMM (O projection) ----------------
template <typename OutT>
__global__ __launch_bounds__(256) void gemm_bt(const ushort* __restrict__ A,
                                               const ushort* __restrict__ B,
                                               OutT* __restrict__ C,
                                               int M, int N, int K) {
  __shared__ __align__(16) ushort lds_a[128 * 32];
  __shared__ __align__(16) ushort lds_b[128 * 32];
  const int tid = threadIdx.x;
  const int w = tid >> 6, lane = tid & 63;
  const int wm = w >> 1, wn = w & 1;
  const int lo = lane & 15, hi = lane >> 4;
  const int m0 = blockIdx.y * 128, n0 = blockIdx.x * 128;
  const int srow = lane >> 2;
  const int scol = (lane & 3) * 8;
  f32x4 acc[4][4] = {};
  const ushort* Ab = A + (size_t)m0 * K;
  const ushort* Bb = B + (size_t)n0 * K;

  for (int k0 = 0; k0 < K; k0 += 32) {
#pragma unroll
    for (int it = 0; it < 2; ++it) {
      const int rb = it * 64 + w * 16;
      async_ld16(Ab + (size_t)(rb + srow) * K + k0 + scol, &lds_a[rb * 32]);
      async_ld16(Bb + (size_t)(rb + srow) * K + k0 + scol, &lds_b[rb * 32]);
    }
    __syncthreads();
    bf16x8 af[4], bfr[4];
#pragma unroll
    for (int i = 0; i < 4; i++) af[i]  = ld_frag(&lds_a[(wm * 64 + i * 16 + lo) * 32 + hi * 8]);
#pragma unroll
    for (int i = 0; i < 4; i++) bfr[i] = ld_frag(&lds_b[(wn * 64 + i * 16 + lo) * 32 + hi * 8]);
#pragma unroll
    for (int mi = 0; mi < 4; mi++)
#pragma unroll
      for (int ni = 0; ni < 4; ni++)
        acc[mi][ni] = mfma16(af[mi], bfr[ni], acc[mi][ni]);
    __syncthreads();
  }
#pragma unroll
  for (int mi = 0; mi < 4; mi++)
#pragma unroll
    for (int ni = 0; ni < 4; ni++) {
      const int col = n0 + wn * 64 + ni * 16 + lo;
#pragma unroll
      for (int r = 0; r < 4; r++) {
        const int row = m0 + wm * 64 + mi * 16 + hi * 4 + r;
        store_c(&C[(size_t)row * N + col], acc[mi][ni][r]);
      }
    }
}

// ---------------- V transpose: v[T][1024] -> vt[8][128][T] ----------------
__global__ __launch_bounds__(256) void transpose_v(const ushort* __restrict__ v,
                                                   ushort* __restrict__ vt) {
  __shared__ ushort tile[64][65];
  const int c0 = blockIdx.x * 64;
  const int t0 = blockIdx.y * 64;
  const int tid = threadIdx.x;
#pragma unroll
  for (int i = 0; i < 16; i++) {
    int idx = tid + i * 256;
    int r = idx >> 6, c = idx & 63;
    tile[r][c] = v[(size_t)(t0 + r) * (NKV * HD) + c0 + c];
  }
  __syncthreads();
#pragma unroll
  for (int i = 0; i < 16; i++) {
    int idx = tid + i * 256;
    int dr = idx >> 6, dc = idx & 63;
    int gc = c0 + dr;
    int kv = gc >> 7, d = gc & 127;
    vt[(size_t)kv * HD * T_SEQ + (size_t)d * T_SEQ + t0 + dc] = tile[dc][dr];
  }
}

// ---------------- flash attention v3 (scratch-free) ----------------
// grid (32 qpairs, 8 kvh, 2 headpairs); 256 thr = 4 waves.
// Same schedule as v2, but K/V prefetch lives in 8 NAMED uint4 registers
// (no lambda-captured arrays -> no scratch demotion across barriers).
__global__ __launch_bounds__(256) void attn_fused3(const ushort* __restrict__ q,   // [T][4096]
                                                   const ushort* __restrict__ k,   // [T][1024]
                                                   const ushort* __restrict__ vt,  // [8][128][T]
                                                   ushort* __restrict__ o) {       // [T][4096]
  __shared__ __align__(16) char sK[64 * 256];    // K[r][c]: byte r*256 + ((c*2)^((r&7)<<4))
  __shared__ __align__(16) char sV[128 * 128];   // Vt[d][t]: byte d*128 + ((t*2)^((d&7)<<4))
  __shared__ __align__(16) ushort sP[4][16][80]; // 80: rows 160B -> 16B-aligned b128 reads

  const int pr  = blockIdx.x;
  const int kvh = blockIdx.y;
  const int hp  = blockIdx.z;
  const int tid = threadIdx.x;
  const int w = tid >> 6, lane = tid & 63;
  const int lo = lane & 15, hi = lane >> 4;
  const int head = (kvh << 2) + (hp << 1) + (w >> 1);
  const int qsub = w & 1;

  const ushort* kbase = k + kvh * HD;
  const ushort* vbase = vt + (size_t)kvh * HD * T_SEQ;

  // per-thread staging geometry (all compile-time-shaped)
  const int krow0 = tid >> 4;            // 0..15; rows krow0+16j
  const int kc_us = (tid & 15) << 3;     // ushort col offset in K row
  const int kcb   = (tid & 15) << 4;     // byte col offset
  const int kswz  = (krow0 & 7) << 4;    // same for all j (16j % 8 == 0)
  const int vrow0 = tid >> 3;            // 0..31; rows vrow0+32j
  const int vc_us = (tid & 7) << 3;
  const int vcb   = (tid & 7) << 4;
  const int vswz  = (vrow0 & 7) << 4;

  uint4 pk0, pk1, pk2, pk3, pv0, pv1, pv2, pv3;

#define ISSUE(K0)                                                                      \
  {                                                                                    \
    const int kk0_ = (K0);                                                             \
    pk0 = *(const uint4*)(kbase + (size_t)(kk0_ + krow0     ) * (NKV * HD) + kc_us);   \
    pk1 = *(const uint4*)(kbase + (size_t)(kk0_ + krow0 + 16) * (NKV * HD) + kc_us);   \
    pk2 = *(const uint4*)(kbase + (size_t)(kk0_ + krow0 + 32) * (NKV * HD) + kc_us);   \
    pk3 = *(const uint4*)(kbase + (size_t)(kk0_ + krow0 + 48) * (NKV * HD) + kc_us);   \
    pv0 = *(const uint4*)(vbase + (size_t)(vrow0      ) * T_SEQ + kk0_ + vc_us);       \
    pv1 = *(const uint4*)(vbase + (size_t)(vrow0 +  32) * T_SEQ + kk0_ + vc_us);       \
    pv2 = *(const uint4*)(vbase + (size_t)(vrow0 +  64) * T_SEQ + kk0_ + vc_us);       \
    pv3 = *(const uint4*)(vbase + (size_t)(vrow0 +  96) * T_SEQ + kk0_ + vc_us);       \
  }

#define COMMIT()                                                    \
  {                                                                 \
    *(uint4*)(sK + (krow0     ) * 256 + (kcb ^ kswz)) = pk0;        \
    *(uint4*)(sK + (krow0 + 16) * 256 + (kcb ^ kswz)) = pk1;        \
    *(uint4*)(sK + (krow0 + 32) * 256 + (kcb ^ kswz)) = pk2;        \
    *(uint4*)(sK + (krow0 + 48) * 256 + (kcb ^ kswz)) = pk3;        \
    *(uint4*)(sV + (vrow0     ) * 128 + (vcb ^ vswz)) = pv0;        \
    *(uint4*)(sV + (vrow0 + 32) * 128 + (vcb ^ vswz)) = pv1;        \
    *(uint4*)(sV + (vrow0 + 64) * 128 + (vcb ^ vswz)) = pv2;        \
    *(uint4*)(sV + (vrow0 + 96) * 128 + (vcb ^ vswz)) = pv3;        \
  }

  bf16x8 aq[4];
  f32x4 oacc[8];
  float m_r[4], l_r[4];
  const float sc = 0.08838834764831845f;  // 1/sqrt(128)

  const int qtA = pr, qtB = 63 - pr;
  const int ntA = qtA / 2 + 1, ntB = qtB / 2 + 1;
  const int total = ntA + ntB;

  // prologue: stage tile (phase A, t=0)
  ISSUE(0);
  COMMIT();
  __syncthreads();

  // load Q for phase A + init state
  {
    const ushort* qp = q + (size_t)(qtA * 32 + qsub * 16 + lo) * DIM + head * HD;
#pragma unroll
    for (int kk = 0; kk < 4; ++kk) aq[kk] = ld_frag(qp + kk * 32 + hi * 8);
  }
#pragma unroll
  for (int r = 0; r < 4; ++r) { m_r[r] = -__builtin_inff(); l_r[r] = 0.f; }
#pragma unroll
  for (int db = 0; db < 8; ++db) oacc[db] = (f32x4){0.f, 0.f, 0.f, 0.f};

  int phase = 0, nt = ntA, qt = qtA, t = 0;
  for (int i = 0; i < total; ++i) {
    const bool last = (t == nt - 1);
    const bool have_next = (i + 1 < total);
    if (have_next) ISSUE(last ? 0 : (t + 1) * 64);

    const int k0 = t * 64;
    // ---- S = Q K^T ----
    f32x4 s[4] = {};
    __builtin_amdgcn_s_setprio(1);
#pragma unroll
    for (int cb = 0; cb < 4; ++cb) {
      const char* kr = sK + (cb * 16 + lo) * 256;
      const int swz = (lo & 7) << 4;
#pragma unroll
      for (int kk = 0; kk < 4; ++kk) {
        bf16x8 bk = *(const bf16x8*)(kr + ((kk * 64 + hi * 16) ^ swz));
        s[cb] = mfma16(aq[kk], bk, s[cb]);
      }
    }
    __builtin_amdgcn_s_setprio(0);
    // ---- scale + causal mask (last tile of phase only) ----
    const int row0 = qt * 32 + qsub * 16 + hi * 4;
#pragma unroll
    for (int cb = 0; cb < 4; ++cb)
#pragma unroll
      for (int r = 0; r < 4; ++r) {
        float v = s[cb][r] * sc;
        if (last && (k0 + cb * 16 + lo) > (row0 + r)) v = -__builtin_inff();
        s[cb][r] = v;
      }
    // ---- online softmax (rows live in 16-lane groups) ----
#pragma unroll
    for (int r = 0; r < 4; ++r) {
      float mx = fmaxf(fmaxf(s[0][r], s[1][r]), fmaxf(s[2][r], s[3][r]));
      mx = fmaxf(mx, __shfl_xor(mx, 1));
      mx = fmaxf(mx, __shfl_xor(mx, 2));
      mx = fmaxf(mx, __shfl_xor(mx, 4));
      mx = fmaxf(mx, __shfl_xor(mx, 8));
      float mnew = fmaxf(m_r[r], mx);
      float corr = __expf(m_r[r] - mnew);
      float rs = 0.f;
#pragma unroll
      for (int cb = 0; cb < 4; ++cb) {
        float p = __expf(s[cb][r] - mnew);
        s[cb][r] = p; rs += p;
      }
      rs += __shfl_xor(rs, 1); rs += __shfl_xor(rs, 2);
      rs += __shfl_xor(rs, 4); rs += __shfl_xor(rs, 8);
      l_r[r] = l_r[r] * corr + rs;
      m_r[r] = mnew;
#pragma unroll
      for (int db = 0; db < 8; ++db) oacc[db][r] *= corr;
    }
    // ---- P -> LDS -> A-frag ----
#pragma unroll
    for (int cb = 0; cb < 4; ++cb)
#pragma unroll
      for (int r = 0; r < 4; ++r)
        sP[w][hi * 4 + r][cb * 16 + lo] = f2bf(s[cb][r]);
    bf16x8 ap[2];
#pragma unroll
    for (int ks = 0; ks < 2; ++ks) ap[ks] = ld_frag(&sP[w][lo][ks * 32 + hi * 8]);
    // ---- O += P V ----
    __builtin_amdgcn_s_setprio(1);
#pragma unroll
    for (int db = 0; db < 8; ++db) {
      const char* vr = sV + (db * 16 + lo) * 128;
      const int swz = (lo & 7) << 4;
#pragma unroll
      for (int ks = 0; ks < 2; ++ks) {
        bf16x8 bv = *(const bf16x8*)(vr + ((ks * 64 + hi * 16) ^ swz));
        oacc[db] = mfma16(ap[ks], bv, oacc[db]);
      }
    }
    __builtin_amdgcn_s_setprio(0);

    __syncthreads();
    if (have_next) COMMIT();
    __syncthreads();

    if (last) {
      // write O for this q-tile
      const int wrow0 = qt * 32 + qsub * 16;
#pragma unroll
      for (int db = 0; db < 8; ++db)
#pragma unroll
        for (int r = 0; r < 4; ++r) {
          float v = oacc[db][r] / l_r[r];
          o[(size_t)(wrow0 + hi * 4 + r) * DIM + head * HD + db * 16 + lo] = f2bf(v);
        }
      if (phase == 0) {
        phase = 1; nt = ntB; qt = qtB; t = 0;
        const ushort* qp = q + (size_t)(qtB * 32 + qsub * 16 + lo) * DIM + head * HD;
#pragma unroll
        for (int kk = 0; kk < 4; ++kk) aq[kk] = ld_frag(qp + kk * 32 + hi * 8);
#pragma unroll
        for (int r = 0; r < 4; ++r) { m_r[r] = -__builtin_inff(); l_r[r] = 0.f; }
#pragma unroll
        for (int db = 0; db < 8; ++db) oacc[db] = (f32x4){0.f, 0.f, 0.f, 0.f};
      }
    } else {
      ++t;
    }
  }
#undef ISSUE
#undef COMMIT
}

// ---------------- launch ----------------
extern "C" void kernel_launch(void* const* d_in, const int* in_sizes, int n_in,
                              void* d_out, int out_size, void* d_ws, size_t ws_size,
                              hipStream_t stream) {
  const float* x  = (const float*)d_in[0];
  const float* wq = (const float*)d_in[1];
  const float* wk = (const float*)d_in[2];
  const float* wv = (const float*)d_in[3];
  const float* wo = (const float*)d_in[4];
  float* out = (float*)d_out;

  char* ws = (char*)d_ws;
  size_t off = 0;
  auto alloc = [&](size_t elems) {
    ushort* p = (ushort*)(ws + off);
    off += ((elems * 2 + 255) & ~(size_t)255);
    return p;
  };
  ushort* xb  = alloc((size_t)T_SEQ * DIM);
  ushort* wqb = alloc((size_t)DIM * DIM);
  ushort* wkb = alloc((size_t)NKV * HD * DIM);
  ushort* wvb = alloc((size_t)NKV * HD * DIM);
  ushort* wob = alloc((size_t)DIM * DIM);
  ushort* qb  = alloc((size_t)T_SEQ * DIM);
  ushort* kb  = alloc((size_t)T_SEQ * NKV * HD);
  ushort* vb  = alloc((size_t)T_SEQ * NKV * HD);
  ushort* vtb = alloc((size_t)NKV * HD * T_SEQ);
  ushort* ab  = alloc((size_t)T_SEQ * DIM);

  auto cvt = [&](const float* src, ushort* dst, size_t n) {
    size_t want = (n / 4 + 255) / 256;
    int blocks = (int)(want < 2048 ? want : 2048);
    cvt_f32_bf16<<<blocks, 256, 0, stream>>>(src, dst, (int)n);
  };
  cvt(x,  xb,  (size_t)T_SEQ * DIM);
  cvt(wq, wqb, (size_t)DIM * DIM);
  cvt(wk, wkb, (size_t)NKV * HD * DIM);
  cvt(wv, wvb, (size_t)NKV * HD * DIM);
  cvt(wo, wob, (size_t)DIM * DIM);

  gemm_qkv<<<dim3(48, 16), 256, 0, stream>>>(xb, wqb, wkb, wvb, qb, kb, vb);
  transpose_v<<<dim3(NKV * HD / 64, T_SEQ / 64), 256, 0, stream>>>(vb, vtb);
  attn_fused3<<<dim3(32, NKV, 2), 256, 0, stream>>>(qb, kb, vtb, ab);
  gemm_bt<float><<<dim3(DIM / 128, T_SEQ / 128), 256, 0, stream>>>(ab, wob, out, T_SEQ, DIM, DIM);
}

// Round 10
// 527.755 us; speedup vs baseline: 2.0567x; 1.0141x over previous
//
#include <hip/hip_runtime.h>
#include <hip/hip_bf16.h>

// GQA prefill: B=1, T=2048, DIM=4096, H=32, KV=8, D=128, causal.
// fused cvt fp32->bf16 -> fused QKV proj (bf16 MFMA) -> V transpose ->
// flash attention v4 (scratch-free + defer-max) -> O proj.

#define T_SEQ 2048
#define DIM 4096
#define NH 32
#define NKV 8
#define HD 128

using f32x4 = __attribute__((ext_vector_type(4))) float;
using bf16x8 = __attribute__((ext_vector_type(8))) __bf16;

#define DEVINLINE __device__ __forceinline__

DEVINLINE ushort f2bf(float f) {
  union { float f; unsigned u; } a; a.f = f;
  unsigned u = a.u;
  u += 0x7fffu + ((u >> 16) & 1u);   // RNE
  return (ushort)(u >> 16);
}

DEVINLINE bf16x8 ld_frag(const ushort* p) { return *(const bf16x8*)p; }

DEVINLINE f32x4 mfma16(bf16x8 a, bf16x8 b, f32x4 c) {
  return __builtin_amdgcn_mfma_f32_16x16x32_bf16(a, b, c, 0, 0, 0);
}

DEVINLINE void async_ld16(const void* g, void* l) {
  __builtin_amdgcn_global_load_lds(
      (__attribute__((address_space(1))) void*)(g),
      (__attribute__((address_space(3))) void*)(l), 16, 0, 0);
}

DEVINLINE void store_c(float* p, float v) { *p = v; }
DEVINLINE void store_c(ushort* p, float v) { *p = f2bf(v); }

// ---------------- fused fp32 -> bf16 conversion (one launch, all 5 tensors) ----------------
__global__ __launch_bounds__(256) void cvt_all(const float* __restrict__ x,  ushort* __restrict__ xb,
                                               const float* __restrict__ wq, ushort* __restrict__ wqb,
                                               const float* __restrict__ wk, ushort* __restrict__ wkb,
                                               const float* __restrict__ wv, ushort* __restrict__ wvb,
                                               const float* __restrict__ wo, ushort* __restrict__ wob) {
  const int tid = blockIdx.x * blockDim.x + threadIdx.x;
  const int stride = gridDim.x * blockDim.x;  // in float4 units
  auto seg = [&](const float* __restrict__ in, ushort* __restrict__ out, int n4) {
    for (int i = tid; i < n4; i += stride) {
      float4 f = ((const float4*)in)[i];
      ushort4 u;
      u.x = f2bf(f.x); u.y = f2bf(f.y); u.z = f2bf(f.z); u.w = f2bf(f.w);
      ((ushort4*)out)[i] = u;
    }
  };
  seg(x,  xb,  (T_SEQ * DIM) / 4);
  seg(wq, wqb, (DIM * DIM) / 4);
  seg(wk, wkb, (NKV * HD * DIM) / 4);
  seg(wv, wvb, (NKV * HD * DIM) / 4);
  seg(wo, wob, (DIM * DIM) / 4);
}

// ---------------- fused QKV GEMM: [2048x4096] x {wq,wk,wv}^T ----------------
// 128x128 tile, BK=32, 4 waves. bx 0..31 -> Q, 32..39 -> K, 40..47 -> V.
__global__ __launch_bounds__(256) void gemm_qkv(const ushort* __restrict__ A,
                                                const ushort* __restrict__ wq,
                                                const ushort* __restrict__ wk,
                                                const ushort* __restrict__ wv,
                                                ushort* __restrict__ qo,
                                                ushort* __restrict__ ko,
                                                ushort* __restrict__ vo) {
  __shared__ __align__(16) ushort lds_a[128 * 32];
  __shared__ __align__(16) ushort lds_b[128 * 32];
  const int K = DIM;
  const int bx = blockIdx.x;
  const ushort* B; ushort* C; int n0, Nc;
  if (bx < 32)      { B = wq + (size_t)bx * 128 * K;        C = qo; n0 = bx * 128;        Nc = DIM; }
  else if (bx < 40) { B = wk + (size_t)(bx - 32) * 128 * K; C = ko; n0 = (bx - 32) * 128; Nc = NKV * HD; }
  else              { B = wv + (size_t)(bx - 40) * 128 * K; C = vo; n0 = (bx - 40) * 128; Nc = NKV * HD; }

  const int tid = threadIdx.x;
  const int w = tid >> 6, lane = tid & 63;
  const int wm = w >> 1, wn = w & 1;
  const int lo = lane & 15, hi = lane >> 4;
  const int m0 = blockIdx.y * 128;
  const int srow = lane >> 2;
  const int scol = (lane & 3) * 8;
  f32x4 acc[4][4] = {};
  const ushort* Ab = A + (size_t)m0 * K;

  for (int k0 = 0; k0 < K; k0 += 32) {
#pragma unroll
    for (int it = 0; it < 2; ++it) {
      const int rb = it * 64 + w * 16;
      async_ld16(Ab + (size_t)(rb + srow) * K + k0 + scol, &lds_a[rb * 32]);
      async_ld16(B  + (size_t)(rb + srow) * K + k0 + scol, &lds_b[rb * 32]);
    }
    __syncthreads();
    bf16x8 af[4], bfr[4];
#pragma unroll
    for (int i = 0; i < 4; i++) af[i]  = ld_frag(&lds_a[(wm * 64 + i * 16 + lo) * 32 + hi * 8]);
#pragma unroll
    for (int i = 0; i < 4; i++) bfr[i] = ld_frag(&lds_b[(wn * 64 + i * 16 + lo) * 32 + hi * 8]);
#pragma unroll
    for (int mi = 0; mi < 4; mi++)
#pragma unroll
      for (int ni = 0; ni < 4; ni++)
        acc[mi][ni] = mfma16(af[mi], bfr[ni], acc[mi][ni]);
    __syncthreads();
  }
#pragma unroll
  for (int mi = 0; mi < 4; mi++)
#pragma unroll
    for (int ni = 0; ni < 4; ni++) {
      const int col = n0 + wn * 64 + ni * 16 + lo;
#pragma unroll
      for (int r = 0; r < 4; r++) {
        const int row = m0 + wm * 64 + mi * 16 + hi * 4 + r;
        C[(size_t)row * Nc + col] = f2bf(acc[mi][ni][r]);
      }
    }
}

// ---------------- generic GEMM (O projection) ----------------
template <typename OutT>
__global__ __launch_bounds__(256) void gemm_bt(const ushort* __restrict__ A,
                                               const ushort* __restrict__ B,
                                               OutT* __restrict__ C,
                                               int M, int N, int K) {
  __shared__ __align__(16) ushort lds_a[128 * 32];
  __shared__ __align__(16) ushort lds_b[128 * 32];
  const int tid = threadIdx.x;
  const int w = tid >> 6, lane = tid & 63;
  const int wm = w >> 1, wn = w & 1;
  const int lo = lane & 15, hi = lane >> 4;
  const int m0 = blockIdx.y * 128, n0 = blockIdx.x * 128;
  const int srow = lane >> 2;
  const int scol = (lane & 3) * 8;
  f32x4 acc[4][4] = {};
  const ushort* Ab = A + (size_t)m0 * K;
  const ushort* Bb = B + (size_t)n0 * K;

  for (int k0 = 0; k0 < K; k0 += 32) {
#pragma unroll
    for (int it = 0; it < 2; ++it) {
      const int rb = it * 64 + w * 16;
      async_ld16(Ab + (size_t)(rb + srow) * K + k0 + scol, &lds_a[rb * 32]);
      async_ld16(Bb + (size_t)(rb + srow) * K + k0 + scol, &lds_b[rb * 32]);
    }
    __syncthreads();
    bf16x8 af[4], bfr[4];
#pragma unroll
    for (int i = 0; i < 4; i++) af[i]  = ld_frag(&lds_a[(wm * 64 + i * 16 + lo) * 32 + hi * 8]);
#pragma unroll
    for (int i = 0; i < 4; i++) bfr[i] = ld_frag(&lds_b[(wn * 64 + i * 16 + lo) * 32 + hi * 8]);
#pragma unroll
    for (int mi = 0; mi < 4; mi++)
#pragma unroll
      for (int ni = 0; ni < 4; ni++)
        acc[mi][ni] = mfma16(af[mi], bfr[ni], acc[mi][ni]);
    __syncthreads();
  }
#pragma unroll
  for (int mi = 0; mi < 4; mi++)
#pragma unroll
    for (int ni = 0; ni < 4; ni++) {
      const int col = n0 + wn * 64 + ni * 16 + lo;
#pragma unroll
      for (int r = 0; r < 4; r++) {
        const int row = m0 + wm * 64 + mi * 16 + hi * 4 + r;
        store_c(&C[(size_t)row * N + col], acc[mi][ni][r]);
      }
    }
}

// ---------------- V transpose: v[T][1024] -> vt[8][128][T] ----------------
__global__ __launch_bounds__(256) void transpose_v(const ushort* __restrict__ v,
                                                   ushort* __restrict__ vt) {
  __shared__ ushort tile[64][65];
  const int c0 = blockIdx.x * 64;
  const int t0 = blockIdx.y * 64;
  const int tid = threadIdx.x;
#pragma unroll
  for (int i = 0; i < 16; i++) {
    int idx = tid + i * 256;
    int r = idx >> 6, c = idx & 63;
    tile[r][c] = v[(size_t)(t0 + r) * (NKV * HD) + c0 + c];
  }
  __syncthreads();
#pragma unroll
  for (int i = 0; i < 16; i++) {
    int idx = tid + i * 256;
    int dr = idx >> 6, dc = idx & 63;
    int gc = c0 + dr;
    int kv = gc >> 7, d = gc & 127;
    vt[(size_t)kv * HD * T_SEQ + (size_t)d * T_SEQ + t0 + dc] = tile[dc][dr];
  }
}

// ---------------- flash attention v4 (scratch-free + defer-max) ----------------
// grid (32 qpairs, 8 kvh, 2 headpairs); 256 thr = 4 waves.
// K/V prefetch in 8 NAMED uint4 registers; T13 defer-max (THR=8) skips the
// O-rescale when the running max grows by <= 8 (wave-uniform branch).
__global__ __launch_bounds__(256) void attn_fused4(const ushort* __restrict__ q,   // [T][4096]
                                                   const ushort* __restrict__ k,   // [T][1024]
                                                   const ushort* __restrict__ vt,  // [8][128][T]
                                                   ushort* __restrict__ o) {       // [T][4096]
  __shared__ __align__(16) char sK[64 * 256];    // K[r][c]: byte r*256 + ((c*2)^((r&7)<<4))
  __shared__ __align__(16) char sV[128 * 128];   // Vt[d][t]: byte d*128 + ((t*2)^((d&7)<<4))
  __shared__ __align__(16) ushort sP[4][16][80]; // rows 160B -> 16B-aligned b128 reads

  const int pr  = blockIdx.x;
  const int kvh = blockIdx.y;
  const int hp  = blockIdx.z;
  const int tid = threadIdx.x;
  const int w = tid >> 6, lane = tid & 63;
  const int lo = lane & 15, hi = lane >> 4;
  const int head = (kvh << 2) + (hp << 1) + (w >> 1);
  const int qsub = w & 1;

  const ushort* kbase = k + kvh * HD;
  const ushort* vbase = vt + (size_t)kvh * HD * T_SEQ;

  // per-thread staging geometry (all compile-time-shaped)
  const int krow0 = tid >> 4;            // 0..15; rows krow0+16j
  const int kc_us = (tid & 15) << 3;     // ushort col offset in K row
  const int kcb   = (tid & 15) << 4;     // byte col offset
  const int kswz  = (krow0 & 7) << 4;    // same for all j (16j % 8 == 0)
  const int vrow0 = tid >> 3;            // 0..31; rows vrow0+32j
  const int vc_us = (tid & 7) << 3;
  const int vcb   = (tid & 7) << 4;
  const int vswz  = (vrow0 & 7) << 4;

  uint4 pk0, pk1, pk2, pk3, pv0, pv1, pv2, pv3;

#define ISSUE(K0)                                                                      \
  {                                                                                    \
    const int kk0_ = (K0);                                                             \
    pk0 = *(const uint4*)(kbase + (size_t)(kk0_ + krow0     ) * (NKV * HD) + kc_us);   \
    pk1 = *(const uint4*)(kbase + (size_t)(kk0_ + krow0 + 16) * (NKV * HD) + kc_us);   \
    pk2 = *(const uint4*)(kbase + (size_t)(kk0_ + krow0 + 32) * (NKV * HD) + kc_us);   \
    pk3 = *(const uint4*)(kbase + (size_t)(kk0_ + krow0 + 48) * (NKV * HD) + kc_us);   \
    pv0 = *(const uint4*)(vbase + (size_t)(vrow0      ) * T_SEQ + kk0_ + vc_us);       \
    pv1 = *(const uint4*)(vbase + (size_t)(vrow0 +  32) * T_SEQ + kk0_ + vc_us);       \
    pv2 = *(const uint4*)(vbase + (size_t)(vrow0 +  64) * T_SEQ + kk0_ + vc_us);       \
    pv3 = *(const uint4*)(vbase + (size_t)(vrow0 +  96) * T_SEQ + kk0_ + vc_us);       \
  }

#define COMMIT()                                                    \
  {                                                                 \
    *(uint4*)(sK + (krow0     ) * 256 + (kcb ^ kswz)) = pk0;        \
    *(uint4*)(sK + (krow0 + 16) * 256 + (kcb ^ kswz)) = pk1;        \
    *(uint4*)(sK + (krow0 + 32) * 256 + (kcb ^ kswz)) = pk2;        \
    *(uint4*)(sK + (krow0 + 48) * 256 + (kcb ^ kswz)) = pk3;        \
    *(uint4*)(sV + (vrow0     ) * 128 + (vcb ^ vswz)) = pv0;        \
    *(uint4*)(sV + (vrow0 + 32) * 128 + (vcb ^ vswz)) = pv1;        \
    *(uint4*)(sV + (vrow0 + 64) * 128 + (vcb ^ vswz)) = pv2;        \
    *(uint4*)(sV + (vrow0 + 96) * 128 + (vcb ^ vswz)) = pv3;        \
  }

  bf16x8 aq[4];
  f32x4 oacc[8];
  float m_r[4], l_r[4];
  const float sc = 0.08838834764831845f;  // 1/sqrt(128)

  const int qtA = pr, qtB = 63 - pr;
  const int ntA = qtA / 2 + 1, ntB = qtB / 2 + 1;
  const int total = ntA + ntB;

  // prologue: stage tile (phase A, t=0)
  ISSUE(0);
  COMMIT();
  __syncthreads();

  // load Q for phase A + init state
  {
    const ushort* qp = q + (size_t)(qtA * 32 + qsub * 16 + lo) * DIM + head * HD;
#pragma unroll
    for (int kk = 0; kk < 4; ++kk) aq[kk] = ld_frag(qp + kk * 32 + hi * 8);
  }
#pragma unroll
  for (int r = 0; r < 4; ++r) { m_r[r] = -__builtin_inff(); l_r[r] = 0.f; }
#pragma unroll
  for (int db = 0; db < 8; ++db) oacc[db] = (f32x4){0.f, 0.f, 0.f, 0.f};

  int phase = 0, nt = ntA, qt = qtA, t = 0;
  for (int i = 0; i < total; ++i) {
    const bool last = (t == nt - 1);
    const bool have_next = (i + 1 < total);
    if (have_next) ISSUE(last ? 0 : (t + 1) * 64);

    const int k0 = t * 64;
    // ---- S = Q K^T ----
    f32x4 s[4] = {};
    __builtin_amdgcn_s_setprio(1);
#pragma unroll
    for (int cb = 0; cb < 4; ++cb) {
      const char* kr = sK + (cb * 16 + lo) * 256;
      const int swz = (lo & 7) << 4;
#pragma unroll
      for (int kk = 0; kk < 4; ++kk) {
        bf16x8 bk = *(const bf16x8*)(kr + ((kk * 64 + hi * 16) ^ swz));
        s[cb] = mfma16(aq[kk], bk, s[cb]);
      }
    }
    __builtin_amdgcn_s_setprio(0);
    // ---- scale + causal mask (last tile of phase only) ----
    const int row0 = qt * 32 + qsub * 16 + hi * 4;
#pragma unroll
    for (int cb = 0; cb < 4; ++cb)
#pragma unroll
      for (int r = 0; r < 4; ++r) {
        float v = s[cb][r] * sc;
        if (last && (k0 + cb * 16 + lo) > (row0 + r)) v = -__builtin_inff();
        s[cb][r] = v;
      }
    // ---- online softmax with defer-max (T13, THR=8) ----
    float mx4[4];
#pragma unroll
    for (int r = 0; r < 4; ++r) {
      float mx = fmaxf(fmaxf(s[0][r], s[1][r]), fmaxf(s[2][r], s[3][r]));
      mx = fmaxf(mx, __shfl_xor(mx, 1));
      mx = fmaxf(mx, __shfl_xor(mx, 2));
      mx = fmaxf(mx, __shfl_xor(mx, 4));
      mx = fmaxf(mx, __shfl_xor(mx, 8));
      mx4[r] = mx;
    }
    bool need = false;
#pragma unroll
    for (int r = 0; r < 4; ++r) need = need || (mx4[r] > m_r[r] + 8.f);
    if (__any(need)) {
#pragma unroll
      for (int r = 0; r < 4; ++r) {
        float mnew = fmaxf(m_r[r], mx4[r]);
        float corr = __expf(m_r[r] - mnew);
        l_r[r] *= corr;
#pragma unroll
        for (int db = 0; db < 8; ++db) oacc[db][r] *= corr;
        m_r[r] = mnew;
      }
    }
#pragma unroll
    for (int r = 0; r < 4; ++r) {
      float rs = 0.f;
#pragma unroll
      for (int cb = 0; cb < 4; ++cb) {
        float p = __expf(s[cb][r] - m_r[r]);
        s[cb][r] = p; rs += p;
      }
      rs += __shfl_xor(rs, 1); rs += __shfl_xor(rs, 2);
      rs += __shfl_xor(rs, 4); rs += __shfl_xor(rs, 8);
      l_r[r] += rs;
    }
    // ---- P -> LDS -> A-frag ----
#pragma unroll
    for (int cb = 0; cb < 4; ++cb)
#pragma unroll
      for (int r = 0; r < 4; ++r)
        sP[w][hi * 4 + r][cb * 16 + lo] = f2bf(s[cb][r]);
    bf16x8 ap[2];
#pragma unroll
    for (int ks = 0; ks < 2; ++ks) ap[ks] = ld_frag(&sP[w][lo][ks * 32 + hi * 8]);
    // ---- O += P V ----
    __builtin_amdgcn_s_setprio(1);
#pragma unroll
    for (int db = 0; db < 8; ++db) {
      const char* vr = sV + (db * 16 + lo) * 128;
      const int swz = (lo & 7) << 4;
#pragma unroll
      for (int ks = 0; ks < 2; ++ks) {
        bf16x8 bv = *(const bf16x8*)(vr + ((ks * 64 + hi * 16) ^ swz));
        oacc[db] = mfma16(ap[ks], bv, oacc[db]);
      }
    }
    __builtin_amdgcn_s_setprio(0);

    __syncthreads();
    if (have_next) COMMIT();
    __syncthreads();

    if (last) {
      // write O for this q-tile
      const int wrow0 = qt * 32 + qsub * 16;
#pragma unroll
      for (int db = 0; db < 8; ++db)
#pragma unroll
        for (int r = 0; r < 4; ++r) {
          float v = oacc[db][r] / l_r[r];
          o[(size_t)(wrow0 + hi * 4 + r) * DIM + head * HD + db * 16 + lo] = f2bf(v);
        }
      if (phase == 0) {
        phase = 1; nt = ntB; qt = qtB; t = 0;
        const ushort* qp = q + (size_t)(qtB * 32 + qsub * 16 + lo) * DIM + head * HD;
#pragma unroll
        for (int kk = 0; kk < 4; ++kk) aq[kk] = ld_frag(qp + kk * 32 + hi * 8);
#pragma unroll
        for (int r = 0; r < 4; ++r) { m_r[r] = -__builtin_inff(); l_r[r] = 0.f; }
#pragma unroll
        for (int db = 0; db < 8; ++db) oacc[db] = (f32x4){0.f, 0.f, 0.f, 0.f};
      }
    } else {
      ++t;
    }
  }
#undef ISSUE
#undef COMMIT
}

// ---------------- launch ----------------
extern "C" void kernel_launch(void* const* d_in, const int* in_sizes, int n_in,
                              void* d_out, int out_size, void* d_ws, size_t ws_size,
                              hipStream_t stream) {
  const float* x  = (const float*)d_in[0];
  const float* wq = (const float*)d_in[1];
  const float* wk = (const float*)d_in[2];
  const float* wv = (const float*)d_in[3];
  const float* wo = (const float*)d_in[4];
  float* out = (float*)d_out;

  char* ws = (char*)d_ws;
  size_t off = 0;
  auto alloc = [&](size_t elems) {
    ushort* p = (ushort*)(ws + off);
    off += ((elems * 2 + 255) & ~(size_t)255);
    return p;
  };
  ushort* xb  = alloc((size_t)T_SEQ * DIM);
  ushort* wqb = alloc((size_t)DIM * DIM);
  ushort* wkb = alloc((size_t)NKV * HD * DIM);
  ushort* wvb = alloc((size_t)NKV * HD * DIM);
  ushort* wob = alloc((size_t)DIM * DIM);
  ushort* qb  = alloc((size_t)T_SEQ * DIM);
  ushort* kb  = alloc((size_t)T_SEQ * NKV * HD);
  ushort* vb  = alloc((size_t)T_SEQ * NKV * HD);
  ushort* vtb = alloc((size_t)NKV * HD * T_SEQ);
  ushort* ab  = alloc((size_t)T_SEQ * DIM);

  cvt_all<<<2048, 256, 0, stream>>>(x, xb, wq, wqb, wk, wkb, wv, wvb, wo, wob);
  gemm_qkv<<<dim3(48, 16), 256, 0, stream>>>(xb, wqb, wkb, wvb, qb, kb, vb);
  transpose_v<<<dim3(NKV * HD / 64, T_SEQ / 64), 256, 0, stream>>>(vb, vtb);
  attn_fused4<<<dim3(32, NKV, 2), 256, 0, stream>>>(qb, kb, vtb, ab);
  gemm_bt<float><<<dim3(DIM / 128, T_SEQ / 128), 256, 0, stream>>>(ab, wob, out, T_SEQ, DIM, DIM);
}